// Round 11
// baseline (201.200 us; speedup 1.0000x reference)
//
#include <hip/hip_runtime.h>

#define BB 4
#define CH 64
#define HW 65536
#define NN 16384
#define NT 128
#define TW 256
#define F2PITCH 72
#define W1OFS 0
#define W2OFS 4096
#define W3OFS 8192
#define WFOFS 12288
#define W2L 0
#define WFL 8192
#define FWS_BYTE 46080
#define PTAB_BYTE 49152
#define PT_ROW 160
#define WS_NEED ((size_t)PTAB_BYTE + (size_t)BB * NN * PT_ROW)

typedef __attribute__((ext_vector_type(8))) short short8;
typedef __attribute__((ext_vector_type(4))) float f32x4;

union frag_u { unsigned short u[8]; short8 v; };
union frag2_u { unsigned short u[8]; unsigned int d[4]; short8 v; };
union bfrag { uint4 qv; short8 v; unsigned short u[8]; };
union half_u { uint4 q[2]; unsigned short u[16]; };

static __device__ __forceinline__ unsigned short f2bf(float x) {
    unsigned int u = __float_as_uint(x);
    return (unsigned short)((u + 0x7fffu + ((u >> 16) & 1u)) >> 16);
}
static __device__ __forceinline__ float bf2f(unsigned short h) {
    return __uint_as_float(((unsigned int)h) << 16);
}
// packed f32->2xbf16 RTNE (identical rounding to f2bf)
static __device__ __forceinline__ unsigned int cvtpk(float a, float b) {
    unsigned int r;
    asm("v_cvt_pk_bf16_f32 %0, %1, %2" : "=v"(r) : "v"(a), "v"(b));
    return r;
}

// ---------------- merged prepass: weights (blocks >= NN/64) + point table ----------------
// fws layout (f32): 0 b1 | 64 b2 | 128 b3 | 192 bf | 256 w_ox | 320 w_oy |
//                   384 w_corr | 448 w_fx | 512 w_fy
__global__ __launch_bounds__(256) void prep(
    const float* __restrict__ xy, const float* __restrict__ f3d,
    const float* __restrict__ lf3d,
    const float* __restrict__ w1, const float* __restrict__ b1,
    const float* __restrict__ w2, const float* __restrict__ b2,
    const float* __restrict__ w3, const float* __restrict__ b3,
    const float* __restrict__ wf, const float* __restrict__ bf,
    unsigned short* __restrict__ wpk, float* __restrict__ fws,
    char* __restrict__ pt)
{
    const int t = threadIdx.x;
    const int bx = blockIdx.x;
    if (bx >= NN / 64) {
        if (blockIdx.y != 0) return;
        const int blk = bx - NN / 64;
        if (blk == 0) {
            for (int i = t; i < 64 * 64; i += 256) {
                const int m = i >> 6, k = i & 63;
                wpk[W1OFS + i] = f2bf(w1[m * 69 + 3 + k]);
            }
        } else if (blk == 1) {
            for (int i = t; i < 64 * 64; i += 256) wpk[W2OFS + i] = f2bf(w2[i]);
        } else if (blk == 2) {
            for (int i = t; i < 64 * 64; i += 256) wpk[W3OFS + i] = f2bf(w3[i]);
        } else if (blk == 3) {
            for (int i = t; i < 64 * 128; i += 256) wpk[WFOFS + i] = f2bf(wf[i]);
        } else if (t < 64) {
            fws[t]       = b1[t];
            fws[64 + t]  = b2[t];
            fws[128 + t] = b3[t];
            fws[192 + t] = bf[t];
            fws[256 + t] = w1[t * 69 + 1];   // offset-x column (f32 path)
            fws[320 + t] = w1[t * 69 + 2];   // offset-y column
            fws[384 + t] = w1[t * 69 + 0];   // corr column
            fws[448 + t] = w1[t * 69 + 67];  // flow-x column
            fws[512 + t] = w1[t * 69 + 68];  // flow-y column
        }
        return;
    }
    const int cq = t >> 6;
    const int l = t & 63;
    const int gn = bx * 64 + l;
    const int b = blockIdx.y;
    half_u r;
#pragma unroll
    for (int i = 0; i < 16; i++)
        r.u[i] = f2bf(f3d[(size_t)(b * CH + cq * 16 + i) * NN + gn]);
    char* row = pt + ((size_t)b * NN + gn) * PT_ROW;
    uint4* rq = (uint4*)row;
    rq[2 * cq] = r.q[0];
    rq[2 * cq + 1] = r.q[1];
    if (cq == 0) {
        float4 e;
        e.x = xy[(size_t)(b * 2 + 0) * NN + gn];
        e.y = xy[(size_t)(b * 2 + 1) * NN + gn];
        e.z = lf3d[(size_t)(b * 2 + 0) * NN + gn];
        e.w = lf3d[(size_t)(b * 2 + 1) * NN + gn];
        *(float4*)(row + 144) = e;
    }
}

// ---------------- weight staging: W2/W3/WF global -> LDS, XOR-swizzled rows ----------------
static __device__ __forceinline__ void wstage(
    const unsigned short* __restrict__ wpk, unsigned short* wl, int tid)
{
#pragma unroll 1
    for (int m = 0; m < 2; m++) {
        const char* g = (const char*)(wpk + W2OFS + m * 4096);
        char* l = (char*)(wl + m * 4096);
        for (int i = tid; i < 512; i += 256) {   // 64 rows x 8 16B-chunks
            const int row = i >> 3, cb = (i & 7) * 16;
            const uint4 v = *(const uint4*)(g + row * 128 + cb);
            *(uint4*)(l + row * 128 + (cb ^ ((row & 7) << 4))) = v;
        }
    }
    {
        const char* g = (const char*)(wpk + WFOFS);
        char* l = (char*)(wl + WFL);
        for (int i = tid; i < 1024; i += 256) {  // 64 rows x 16 16B-chunks
            const int row = i >> 4, cb = (i & 15) * 16;
            const uint4 v = *(const uint4*)(g + row * 256 + cb);
            *(uint4*)(l + row * 256 + (cb ^ ((row & 7) << 4))) = v;
        }
    }
}

// ---------------- per-tile prefetch register set ----------------
struct pref_t {
    float4 fv[8];       // feat2d tile slice (8 channels x 4 px)
    bfrag g4[2][2];     // gathered 3D rows in MFMA-B fragment layout
    float4 e;           // xy / lf3d extras (lane<32)
    float lfx, lfy;     // lf2d at that px
};

static __device__ __forceinline__ void tile_load(
    pref_t& P, const float* __restrict__ feat2d, const float* __restrict__ lf2d,
    const char* __restrict__ ptab, int b, int p_base, int w, int lane,
    int i0, int i1)
{
    const int ci = lane >> 3, qd = lane & 7;
    const int px0 = 32 * w + qd * 4;
#pragma unroll
    for (int cc = 0; cc < 8; cc++)
        P.fv[cc] = *(const float4*)(feat2d + (size_t)(b * CH + ci * 8 + cc) * HW + p_base + px0);
    const int q = lane >> 4;
    const uint4* r0 = (const uint4*)(ptab + ((size_t)b * NN + i0) * PT_ROW);
    const uint4* r1 = (const uint4*)(ptab + ((size_t)b * NN + i1) * PT_ROW);
#pragma unroll
    for (int kt = 0; kt < 2; kt++) {
        P.g4[0][kt].qv = r0[kt * 4 + (q & 3)];
        P.g4[1][kt].qv = r1[kt * 4 + (q & 3)];
    }
    if (lane < 32) {
        const char* re = (const char*)(lane >= 16 ? r1 : r0);
        P.e = *(const float4*)(re + 144);
        P.lfx = lf2d[(size_t)(b * 2 + 0) * HW + p_base + 32 * w + lane];
        P.lfy = lf2d[(size_t)(b * 2 + 1) * HW + p_base + 32 * w + lane];
    }
}

static __device__ __forceinline__ void tile_stage(
    const pref_t& P, unsigned short* F2, int w, int lane)
{
    const int ci = lane >> 3, qd = lane & 7;
    const int px0 = 32 * w + qd * 4;
#pragma unroll
    for (int px = 0; px < 4; px++) {
        frag2_u fr;
#pragma unroll
        for (int cc = 0; cc < 4; cc++)
            fr.d[cc] = cvtpk(((const float*)&P.fv[2 * cc])[px], ((const float*)&P.fv[2 * cc + 1])[px]);
        *(short8*)&F2[(px0 + px) * F2PITCH + ci * 8] = fr.v;
    }
}

static __device__ __forceinline__ void tile_corr(
    const pref_t& P, const unsigned short* F2, float* offsS, float* auxS,
    int p_base, int w, int lane, int q, int ln)
{
    float ca0 = 0.f, ca1 = 0.f;
#pragma unroll
    for (int kt = 0; kt < 2; kt++) {
        frag_u f0, f1;
        f0.v = *(const short8*)&F2[(32 * w + ln) * F2PITCH + kt * 32 + q * 8];
        f1.v = *(const short8*)&F2[(32 * w + 16 + ln) * F2PITCH + kt * 32 + q * 8];
#pragma unroll
        for (int j = 0; j < 8; j++) {
            ca0 += bf2f(f0.u[j]) * bf2f(P.g4[0][kt].u[j]);
            ca1 += bf2f(f1.u[j]) * bf2f(P.g4[1][kt].u[j]);
        }
    }
    ca0 += __shfl_xor(ca0, 16); ca0 += __shfl_xor(ca0, 32);
    ca1 += __shfl_xor(ca1, 16); ca1 += __shfl_xor(ca1, 32);
    if (lane < 32) {
        const int n = 32 * w + lane;
        const int p = p_base + n;
        offsS[n] = P.e.x - (float)(p & 255);
        offsS[NT + n] = P.e.y - (float)(p >> 8);
        auxS[n] = (lane >= 16 ? ca1 : ca0) * (1.0f / 64.0f);
        auxS[NT + n] = P.e.z - P.lfx;
        auxS[2 * NT + n] = P.e.w - P.lfy;
    }
}

// ---------------- dual-tile reg-exchange layer: A loaded ONCE, both tiles computed -------
template<int RB>
static __device__ __forceinline__ void layer_reg2(
    const unsigned short* wrow,
    const unsigned int pkHA[4][2][2], const unsigned int pkLA[4][2][2],
    const unsigned int pkHB[4][2][2], const unsigned int pkLB[4][2][2],
    int bpa, int bpb, int qh, int ln, int q, int swz,
    f32x4 accA[4][2], f32x4 accB[4][2])
{
#pragma unroll
    for (int kt = 0; kt < 2; kt++) {
        const int kb = (kt * 32 + q * 8) * 2;
        short8 A[4];
#pragma unroll
        for (int mi = 0; mi < 4; mi++)
            A[mi] = *(const short8*)((const char*)wrow + (mi * 16 + ln) * RB + (kb ^ swz));
#pragma unroll
        for (int ni = 0; ni < 2; ni++) {
            frag2_u bhA, blA, bhB, blB;
#pragma unroll
            for (int p = 0; p < 4; p++) {
                const int src = (p >> 1) ? bpb : bpa;
                unsigned h0 = (unsigned)__builtin_amdgcn_ds_bpermute(src, (int)pkHA[kt * 2 + 0][ni][p & 1]);
                unsigned h1 = (unsigned)__builtin_amdgcn_ds_bpermute(src, (int)pkHA[kt * 2 + 1][ni][p & 1]);
                bhA.d[p] = qh ? h1 : h0;
                unsigned l0 = (unsigned)__builtin_amdgcn_ds_bpermute(src, (int)pkLA[kt * 2 + 0][ni][p & 1]);
                unsigned l1 = (unsigned)__builtin_amdgcn_ds_bpermute(src, (int)pkLA[kt * 2 + 1][ni][p & 1]);
                blA.d[p] = qh ? l1 : l0;
                h0 = (unsigned)__builtin_amdgcn_ds_bpermute(src, (int)pkHB[kt * 2 + 0][ni][p & 1]);
                h1 = (unsigned)__builtin_amdgcn_ds_bpermute(src, (int)pkHB[kt * 2 + 1][ni][p & 1]);
                bhB.d[p] = qh ? h1 : h0;
                l0 = (unsigned)__builtin_amdgcn_ds_bpermute(src, (int)pkLB[kt * 2 + 0][ni][p & 1]);
                l1 = (unsigned)__builtin_amdgcn_ds_bpermute(src, (int)pkLB[kt * 2 + 1][ni][p & 1]);
                blB.d[p] = qh ? l1 : l0;
            }
            __builtin_amdgcn_s_setprio(1);
#pragma unroll
            for (int mi = 0; mi < 4; mi++) {
                accA[mi][ni] = __builtin_amdgcn_mfma_f32_16x16x32_bf16(A[mi], bhA.v, accA[mi][ni], 0, 0, 0);
                accA[mi][ni] = __builtin_amdgcn_mfma_f32_16x16x32_bf16(A[mi], blA.v, accA[mi][ni], 0, 0, 0);
                accB[mi][ni] = __builtin_amdgcn_mfma_f32_16x16x32_bf16(A[mi], bhB.v, accB[mi][ni], 0, 0, 0);
                accB[mi][ni] = __builtin_amdgcn_mfma_f32_16x16x32_bf16(A[mi], blB.v, accB[mi][ni], 0, 0, 0);
            }
            __builtin_amdgcn_s_setprio(0);
        }
    }
}

static __device__ __forceinline__ void zero_acc(f32x4 acc[4][2]) {
#pragma unroll
    for (int mi = 0; mi < 4; mi++)
#pragma unroll
        for (int ni = 0; ni < 2; ni++)
#pragma unroll
            for (int r = 0; r < 4; r++) acc[mi][ni][r] = 0.f;
}

// epilogue: leaky(acc + bias [+ rank-5 f32 fix]) -> packed bf16 hi/lo rails in registers
static __device__ __forceinline__ void epi_pack(
    f32x4 acc[4][2], const float* __restrict__ fws, int bofs, bool off_fix,
    const float* offsp, const float* auxp,
    unsigned int pkH[4][2][2], unsigned int pkL[4][2][2],
    int w, int ln, int q)
{
#pragma unroll
    for (int mi = 0; mi < 4; mi++) {
        const float4 bias = *(const float4*)(fws + bofs + mi * 16 + q * 4);
        float4 wox = bias, woy = bias, wco = bias, wfx = bias, wfy = bias;
        if (off_fix) {
            wox = *(const float4*)(fws + 256 + mi * 16 + q * 4);
            woy = *(const float4*)(fws + 320 + mi * 16 + q * 4);
            wco = *(const float4*)(fws + 384 + mi * 16 + q * 4);
            wfx = *(const float4*)(fws + 448 + mi * 16 + q * 4);
            wfy = *(const float4*)(fws + 512 + mi * 16 + q * 4);
        }
#pragma unroll
        for (int ni = 0; ni < 2; ni++) {
            const int nr = 32 * w + ni * 16 + ln;
            float ox = 0.f, oy = 0.f, co = 0.f, fx = 0.f, fy = 0.f;
            if (off_fix) {
                ox = offsp[nr]; oy = offsp[NT + nr];
                co = auxp[nr];  fx = auxp[NT + nr]; fy = auxp[2 * NT + nr];
            }
            float av[4];
#pragma unroll
            for (int r = 0; r < 4; r++) {
                float a = acc[mi][ni][r] + ((const float*)&bias)[r];
                if (off_fix) {
                    a += ((const float*)&wox)[r] * ox + ((const float*)&woy)[r] * oy;
                    a += ((const float*)&wco)[r] * co;
                    a += ((const float*)&wfx)[r] * fx + ((const float*)&wfy)[r] * fy;
                }
                av[r] = fmaxf(a, 0.1f * a);
            }
#pragma unroll
            for (int t = 0; t < 2; t++) {
                const unsigned hh = cvtpk(av[2 * t], av[2 * t + 1]);
                const float l0 = av[2 * t]     - __uint_as_float(hh << 16);
                const float l1 = av[2 * t + 1] - __uint_as_float(hh & 0xffff0000u);
                pkH[mi][ni][t] = hh;
                pkL[mi][ni][t] = cvtpk(l0, l1);
            }
        }
    }
}

static __device__ __forceinline__ void out_store(
    f32x4 acc[4][2], const float* __restrict__ fws, float* __restrict__ out,
    int b, int p_base, int w, int ln, int q)
{
#pragma unroll
    for (int mi = 0; mi < 4; mi++) {
        const float4 bias = *(const float4*)(fws + 192 + mi * 16 + q * 4);
#pragma unroll
        for (int ni = 0; ni < 2; ni++) {
#pragma unroll
            for (int r = 0; r < 4; r++) {
                float a = acc[mi][ni][r] + ((const float*)&bias)[r];
                a = fmaxf(a, 0.1f * a);
                const int m = mi * 16 + q * 4 + r;
                out[(size_t)(b * CH + m) * HW + p_base + 32 * w + ni * 16 + ln] = a;
            }
        }
    }
}

// ---------------- main fused kernel: 2 tiles INTERLEAVED per wave (dual chains) -----------
// Each wave carries two independent dependency chains (tiles A,B); every phase issues A then
// B back-to-back so chain B's instructions fill chain A's latency holes in-order. Weights
// (A-fragments) and wstage are shared between tiles. LDS = 74,752 B -> 2 blocks/CU.
__global__ __launch_bounds__(256, 2) void fuse(
    const float* __restrict__ feat2d, const float* __restrict__ lf2d,
    const int* __restrict__ nn,
    const unsigned short* __restrict__ wpk, const float* __restrict__ fws,
    const char* __restrict__ ptab,
    float* __restrict__ out)
{
    __shared__ unsigned short F2A[NT * F2PITCH];  // 18432 B
    __shared__ unsigned short F2B[NT * F2PITCH];  // 18432 B
    __shared__ unsigned short Wl[16384];          // 32768 B (W2/W3/WF, swizzled)
    __shared__ float offsA[2 * NT];
    __shared__ float auxA[3 * NT];
    __shared__ float offsB[2 * NT];
    __shared__ float auxB[3 * NT];

    const int tid = threadIdx.x;
    const int w = tid >> 6, lane = tid & 63;
    const int q = lane >> 4, ln = lane & 15;
    const int b = blockIdx.y;
    const int p0 = blockIdx.x * TW;
    const int pA = p0, pB = p0 + NT;

    const int bpa = (((lane >> 4) & 1) * 32 + ln) * 4;  // bpermute byte addrs
    const int bpb = bpa + 64;
    const int qh = q >> 1;
    const int swz = (ln & 7) << 4;

    const int i0A = nn[(size_t)b * HW + pA + 32 * w + ln];
    const int i1A = nn[(size_t)b * HW + pA + 32 * w + 16 + ln];
    const int i0B = nn[(size_t)b * HW + pB + 32 * w + ln];
    const int i1B = nn[(size_t)b * HW + pB + 32 * w + 16 + ln];

    pref_t PA, PB;
    tile_load(PA, feat2d, lf2d, ptab, b, pA, w, lane, i0A, i1A);
    tile_load(PB, feat2d, lf2d, ptab, b, pB, w, lane, i0B, i1B);
    wstage(wpk, Wl, tid);          // gather/feat2d HBM latency hides under this
    __syncthreads();

    // W1 A-fragments from global (L2-hot, shared by both tiles)
    short8 A1[2][4];
#pragma unroll
    for (int kt = 0; kt < 2; kt++)
#pragma unroll
        for (int mi = 0; mi < 4; mi++)
            A1[kt][mi] = *(const short8*)(wpk + W1OFS + (mi * 16 + ln) * 64 + kt * 32 + q * 8);

    tile_stage(PA, F2A, w, lane);
    tile_stage(PB, F2B, w, lane);
    tile_corr(PA, F2A, offsA, auxA, pA, w, lane, q, ln);
    tile_corr(PB, F2B, offsB, auxB, pB, w, lane, q, ln);

    unsigned int pkHA[4][2][2], pkLA[4][2][2], pkHB[4][2][2], pkLB[4][2][2];
    f32x4 accA[4][2], accB[4][2];
    // L1: B straight from gather registers; A shared
    zero_acc(accA); zero_acc(accB);
#pragma unroll
    for (int kt = 0; kt < 2; kt++) {
#pragma unroll
        for (int ni = 0; ni < 2; ni++) {
            __builtin_amdgcn_s_setprio(1);
#pragma unroll
            for (int mi = 0; mi < 4; mi++) {
                accA[mi][ni] = __builtin_amdgcn_mfma_f32_16x16x32_bf16(A1[kt][mi], PA.g4[ni][kt].v, accA[mi][ni], 0, 0, 0);
                accB[mi][ni] = __builtin_amdgcn_mfma_f32_16x16x32_bf16(A1[kt][mi], PB.g4[ni][kt].v, accB[mi][ni], 0, 0, 0);
            }
            __builtin_amdgcn_s_setprio(0);
        }
    }
    epi_pack(accA, fws, 0, true, offsA, auxA, pkHA, pkLA, w, ln, q);
    epi_pack(accB, fws, 0, true, offsB, auxB, pkHB, pkLB, w, ln, q);
    // L2, L3 (rolled; A-fragments shared between tiles)
#pragma unroll 1
    for (int l = 0; l < 2; l++) {
        zero_acc(accA); zero_acc(accB);
        layer_reg2<128>(Wl + W2L + (l << 12), pkHA, pkLA, pkHB, pkLB,
                        bpa, bpb, qh, ln, q, swz, accA, accB);
        epi_pack(accA, fws, 64 + (l << 6), false, offsA, auxA, pkHA, pkLA, w, ln, q);
        epi_pack(accB, fws, 64 + (l << 6), false, offsB, auxB, pkHB, pkLB, w, ln, q);
    }
    // Lf: k 0-63 via reg exchange (hi+lo); k 64-127 from F2 tiles (hi only)
    zero_acc(accA); zero_acc(accB);
    layer_reg2<256>(Wl + WFL, pkHA, pkLA, pkHB, pkLB, bpa, bpb, qh, ln, q, swz, accA, accB);
#pragma unroll
    for (int kt = 2; kt < 4; kt++) {
        const int kb = (kt * 32 + q * 8) * 2;
        short8 A[4];
#pragma unroll
        for (int mi = 0; mi < 4; mi++)
            A[mi] = *(const short8*)((const char*)(Wl + WFL) + (mi * 16 + ln) * 256 + (kb ^ swz));
#pragma unroll
        for (int ni = 0; ni < 2; ni++) {
            const int nr = 32 * w + ni * 16 + ln;
            frag_u fhA, fhB;
            fhA.v = *(const short8*)&F2A[nr * F2PITCH + (kt - 2) * 32 + q * 8];
            fhB.v = *(const short8*)&F2B[nr * F2PITCH + (kt - 2) * 32 + q * 8];
            __builtin_amdgcn_s_setprio(1);
#pragma unroll
            for (int mi = 0; mi < 4; mi++) {
                accA[mi][ni] = __builtin_amdgcn_mfma_f32_16x16x32_bf16(A[mi], fhA.v, accA[mi][ni], 0, 0, 0);
                accB[mi][ni] = __builtin_amdgcn_mfma_f32_16x16x32_bf16(A[mi], fhB.v, accB[mi][ni], 0, 0, 0);
            }
            __builtin_amdgcn_s_setprio(0);
        }
    }
    out_store(accA, fws, out, b, pA, w, ln, q);
    out_store(accB, fws, out, b, pB, w, ln, q);
}

// ---------------- fallback: used only if ws too small ----------------
__global__ __launch_bounds__(256) void fuse_slow(
    const float* __restrict__ feat2d, const float* __restrict__ lf2d,
    const float* __restrict__ xy, const float* __restrict__ feat3d,
    const float* __restrict__ lf3d, const int* __restrict__ nn,
    const float* __restrict__ w1, const float* __restrict__ b1,
    const float* __restrict__ w2, const float* __restrict__ b2,
    const float* __restrict__ w3, const float* __restrict__ b3,
    const float* __restrict__ wf, const float* __restrict__ bfv,
    float* __restrict__ out)
{
    const int p = blockIdx.x * 256 + threadIdx.x;
    const int b = blockIdx.y;
    const int idx = nn[(size_t)b * HW + p];
    const float* f3 = feat3d + (size_t)b * CH * NN + idx;
    float g[CH];
#pragma unroll
    for (int c = 0; c < CH; c++) g[c] = f3[(size_t)c * NN];
    const float fl3x = lf3d[(size_t)(b * 2 + 0) * NN + idx];
    const float fl3y = lf3d[(size_t)(b * 2 + 1) * NN + idx];
    const float xyx = xy[(size_t)(b * 2 + 0) * NN + idx];
    const float xyy = xy[(size_t)(b * 2 + 1) * NN + idx];
    const float* f2p = feat2d + (size_t)b * CH * HW + p;
    float corr = 0.f;
#pragma unroll
    for (int c = 0; c < CH; c++) corr += f2p[(size_t)c * HW] * g[c];
    corr *= (1.f / 64.f);
    float xin[69];
    xin[0] = corr;
    xin[1] = xyx - (float)(p & 255);
    xin[2] = xyy - (float)(p >> 8);
#pragma unroll
    for (int c = 0; c < CH; c++) xin[3 + c] = g[c];
    xin[67] = fl3x - lf2d[(size_t)(b * 2 + 0) * HW + p];
    xin[68] = fl3y - lf2d[(size_t)(b * 2 + 1) * HW + p];
    float x1[64], x2[64], x3[64], accv[64];
#pragma unroll
    for (int o = 0; o < 64; o++) {
        float a = b1[o];
#pragma unroll
        for (int k = 0; k < 69; k++) a += w1[o * 69 + k] * xin[k];
        x1[o] = (a >= 0.f) ? a : 0.1f * a;
    }
#pragma unroll
    for (int o = 0; o < 64; o++) {
        float a = b2[o];
#pragma unroll
        for (int k = 0; k < 64; k++) a += w2[o * 64 + k] * x1[k];
        x2[o] = (a >= 0.f) ? a : 0.1f * a;
    }
#pragma unroll
    for (int o = 0; o < 64; o++) {
        float a = b3[o];
#pragma unroll
        for (int k = 0; k < 64; k++) a += w3[o * 64 + k] * x2[k];
        x3[o] = (a >= 0.f) ? a : 0.1f * a;
    }
#pragma unroll
    for (int o = 0; o < 64; o++) {
        float a = bfv[o];
#pragma unroll
        for (int k = 0; k < 64; k++) a += wf[o * 128 + k] * x3[k];
        accv[o] = a;
    }
#pragma unroll
    for (int k = 0; k < 64; k++) {
        const float f = f2p[(size_t)k * HW];
#pragma unroll
        for (int o = 0; o < 64; o++) accv[o] += wf[o * 128 + 64 + k] * f;
    }
#pragma unroll
    for (int o = 0; o < 64; o++) {
        float a = accv[o];
        a = (a >= 0.f) ? a : 0.1f * a;
        out[(size_t)(b * CH + o) * HW + p] = a;
    }
}

extern "C" void kernel_launch(void* const* d_in, const int* in_sizes, int n_in,
                              void* d_out, int out_size, void* d_ws, size_t ws_size,
                              hipStream_t stream)
{
    const float* xy   = (const float*)d_in[0];
    const float* f2d  = (const float*)d_in[1];
    const float* f3d  = (const float*)d_in[2];
    const float* lf2d = (const float*)d_in[3];
    const float* lf3d = (const float*)d_in[4];
    const int*   nn   = (const int*)d_in[5];
    const float* w1 = (const float*)d_in[6];
    const float* b1 = (const float*)d_in[7];
    const float* w2 = (const float*)d_in[8];
    const float* b2 = (const float*)d_in[9];
    const float* w3 = (const float*)d_in[10];
    const float* b3 = (const float*)d_in[11];
    const float* wf = (const float*)d_in[12];
    const float* bf = (const float*)d_in[13];

    if (ws_size >= WS_NEED) {
        unsigned short* wpk = (unsigned short*)d_ws;
        float* fws = (float*)((char*)d_ws + FWS_BYTE);
        char* pt = (char*)d_ws + PTAB_BYTE;
        prep<<<dim3(NN / 64 + 5, BB), 256, 0, stream>>>(xy, f3d, lf3d,
                                                        w1, b1, w2, b2, w3, b3, wf, bf,
                                                        wpk, fws, pt);
        fuse<<<dim3(HW / TW, BB), 256, 0, stream>>>(f2d, lf2d, nn, wpk, fws, pt, (float*)d_out);
    } else {
        fuse_slow<<<dim3(HW / 256, BB), 256, 0, stream>>>(f2d, lf2d, xy, f3d, lf3d, nn,
                                                          w1, b1, w2, b2, w3, b3, wf, bf,
                                                          (float*)d_out);
    }
}